// Round 7
// baseline (110.231 us; speedup 1.0000x reference)
//
#include <hip/hip_runtime.h>

typedef __bf16  bf16x8 __attribute__((ext_vector_type(8)));
typedef float   f32x4  __attribute__((ext_vector_type(4)));
typedef short   short8 __attribute__((ext_vector_type(8)));

static __device__ __forceinline__ unsigned short f2bf(float f) {
  union { float f; unsigned int u; } v; v.f = f;
  unsigned int u = v.u;
  u += 0x7fffu + ((u >> 16) & 1u);   // round-to-nearest-even
  return (unsigned short)(u >> 16);
}

// e2m1 decode: code = sign<<3 | e<<1 | m ; values {0,.5,1,1.5,2,3,4,6} * sign
static __device__ __forceinline__ float fp4_decode(int qc) {
  int e = (qc >> 1) & 3;
  float m = (float)(qc & 1);
  float mag = (e == 0) ? (0.5f * m)
                       : ((2.0f + m) * 0.5f * (float)(1 << (e - 1)));
  return (qc & 8) ? -mag : mag;
}

// Fused prep: blocks [0, nblkW/256) dequant W; rest convert x.
__global__ __launch_bounds__(256) void w4a16_prep(
    const int* __restrict__ wq, const float* __restrict__ wsc,
    short* __restrict__ wout, int nblkW,
    const float* __restrict__ x, short* __restrict__ xb, int n8) {
  const int nbW = nblkW >> 8;
  if ((int)blockIdx.x < nbW) {
    int idx = blockIdx.x * 256 + threadIdx.x;
    if (idx >= nblkW) return;
    float s = wsc[idx];
    const int4* qp = (const int4*)wq + (size_t)idx * 4;
    int4 q0 = qp[0], q1 = qp[1], q2 = qp[2], q3 = qp[3];
    short8 r0, r1;
    r0[0] = (short)f2bf(fp4_decode(q0.x) * s);
    r0[1] = (short)f2bf(fp4_decode(q0.y) * s);
    r0[2] = (short)f2bf(fp4_decode(q0.z) * s);
    r0[3] = (short)f2bf(fp4_decode(q0.w) * s);
    r0[4] = (short)f2bf(fp4_decode(q1.x) * s);
    r0[5] = (short)f2bf(fp4_decode(q1.y) * s);
    r0[6] = (short)f2bf(fp4_decode(q1.z) * s);
    r0[7] = (short)f2bf(fp4_decode(q1.w) * s);
    r1[0] = (short)f2bf(fp4_decode(q2.x) * s);
    r1[1] = (short)f2bf(fp4_decode(q2.y) * s);
    r1[2] = (short)f2bf(fp4_decode(q2.z) * s);
    r1[3] = (short)f2bf(fp4_decode(q2.w) * s);
    r1[4] = (short)f2bf(fp4_decode(q3.x) * s);
    r1[5] = (short)f2bf(fp4_decode(q3.y) * s);
    r1[6] = (short)f2bf(fp4_decode(q3.z) * s);
    r1[7] = (short)f2bf(fp4_decode(q3.w) * s);
    short8* op = (short8*)wout + (size_t)idx * 2;
    op[0] = r0;
    op[1] = r1;
  } else {
    int idx = (blockIdx.x - nbW) * 256 + threadIdx.x;
    if (idx >= n8) return;
    const float4* xp = (const float4*)x + (size_t)idx * 2;
    float4 a = xp[0], b = xp[1];
    short8 r;
    r[0] = (short)f2bf(a.x); r[1] = (short)f2bf(a.y);
    r[2] = (short)f2bf(a.z); r[3] = (short)f2bf(a.w);
    r[4] = (short)f2bf(b.x); r[5] = (short)f2bf(b.y);
    r[6] = (short)f2bf(b.z); r[7] = (short)f2bf(b.w);
    ((short8*)xb)[idx] = r;
  }
}

// ---------------------------------------------------------------------------
// C[M,N] = A[M,K] * B[N,K]^T, bf16 in, fp32 out.
// BM=128 x BN=256, BK=64, 4 waves (1M x 4N), per-wave 128x64 (8x4 frags).
// Read ratio: 384 B LDS-read per MFMA (vs 512 at 64x64 waves); per tile:
// reads 96KB (750cy) + writes 48KB (375cy) < MFMA 1242cy -> MFMA-bound.
// NBUF=2 (96KB LDS, 1 block/CU). One barrier per tile:
// {reads kk0 (12) -> stage t+1 (12) -> reads kk1 (12) -> 32 MFMA kk0 ->
//  32 MFMA kk1 -> sched_barrier -> vmcnt(0) (= t+1's 12 loads, issued a full
//  tile earlier) -> s_barrier}. Compiler counted-lgkm lets MFMA kk0 start
// after the first 12 reads; rest service under the MFMA shadow.
// Swizzle (T2, R2-verified): 16B-chunk c XOR (row&7) on SOURCE and READ.
// ---------------------------------------------------------------------------
#define BM 128
#define BN 256
#define BK 64
#define ASZ (BM * BK)          // 8192 shorts = 16KB
#define BSZ (BN * BK)          // 16384 shorts = 32KB

__global__ __launch_bounds__(256, 1) void w4a16_gemm_w4(
    const short* __restrict__ A, const short* __restrict__ B,
    float* __restrict__ C, int M, int N, int K) {
  __shared__ __attribute__((aligned(16))) short As[2 * ASZ];  // 32KB
  __shared__ __attribute__((aligned(16))) short Bs[2 * BSZ];  // 64KB

  const int tid  = threadIdx.x;
  const int lane = tid & 63;
  const int wc   = tid >> 6;      // 0..3 (N); wave covers all 128 M-rows

  const int bm = blockIdx.y * BM;
  const int bn = blockIdx.x * BN;

  f32x4 acc[8][4] = {};           // [m-frag 0..7][n-frag 0..3]

  const int fr    = lane & 15;
  const int klane = lane >> 4;    // 16B chunk within 32-elem k-slice
  const int xv    = fr & 7;       // read-side swizzle XOR

  const size_t rowbytes = (size_t)K * 2;

  // ---- staging addresses (loop-invariant; only kt varies).
  size_t aoff[4];  int aldso[4];
#pragma unroll
  for (int r = 0; r < 4; ++r) {
    int u = r * 256 + tid;               // 0..1023
    int row = u >> 3, c = u & 7;
    int csrc = c ^ (row & 7);
    aoff[r]  = (size_t)(bm + row) * rowbytes + (size_t)csrc * 16;
    aldso[r] = u * 16;
  }
  size_t boff[8];  int bldso[8];
#pragma unroll
  for (int r = 0; r < 8; ++r) {
    int u = r * 256 + tid;               // 0..2047
    int row = u >> 3, c = u & 7;
    int csrc = c ^ (row & 7);
    boff[r]  = (size_t)(bn + row) * rowbytes + (size_t)csrc * 16;
    bldso[r] = u * 16;
  }
  const char* Ag = (const char*)A;
  const char* Bg = (const char*)B;

#define STAGE_A(bufbase, koff2, r)                                              \
  __builtin_amdgcn_global_load_lds(                                             \
      (const __attribute__((address_space(1))) unsigned int*)(Ag + aoff[r] + (koff2)), \
      (__attribute__((address_space(3))) unsigned int*)((char*)(bufbase) + aldso[r]),  \
      16, 0, 0)
#define STAGE_B(bufbase, koff2, r)                                              \
  __builtin_amdgcn_global_load_lds(                                             \
      (const __attribute__((address_space(1))) unsigned int*)(Bg + boff[r] + (koff2)), \
      (__attribute__((address_space(3))) unsigned int*)((char*)(bufbase) + bldso[r]),  \
      16, 0, 0)

  // swizzled fragment reads (rows are 128B = 8 chunks)
  auto readA = [&](const short* Ab, int mi, int kk) -> bf16x8 {
    int row = mi * 16 + fr;                    // all 128 rows belong to wave
    int c = kk * 4 + klane;
    return *(const bf16x8*)((const char*)Ab + (size_t)row * 128 + ((c ^ xv) << 4));
  };
  auto readB = [&](const short* Bb, int ni, int kk) -> bf16x8 {
    int row = wc * 64 + ni * 16 + fr;
    int c = kk * 4 + klane;
    return *(const bf16x8*)((const char*)Bb + (size_t)row * 128 + ((c ^ xv) << 4));
  };

  const int NT = K / BK;   // 64

  // ---- prologue: stage tile 0 into buf0; confirm; publish.
  {
    char* A0 = (char*)As; char* B0 = (char*)Bs;
    STAGE_A(A0, 0, 0); STAGE_A(A0, 0, 1); STAGE_A(A0, 0, 2); STAGE_A(A0, 0, 3);
    STAGE_B(B0, 0, 0); STAGE_B(B0, 0, 1); STAGE_B(B0, 0, 2); STAGE_B(B0, 0, 3);
    STAGE_B(B0, 0, 4); STAGE_B(B0, 0, 5); STAGE_B(B0, 0, 6); STAGE_B(B0, 0, 7);
  }
  asm volatile("s_waitcnt vmcnt(0)");
  __builtin_amdgcn_s_barrier();

#define TILE_BODY(t_, CURA, CURB, NXTA, NXTB)                                   \
  do {                                                                          \
    bf16x8 af0[8], bf0[4], af1[8], bf1[4];                                      \
    /* reads kk0 first (MFMA0's deps head the LDS queue) */                     \
    _Pragma("unroll") for (int mi = 0; mi < 8; ++mi) af0[mi] = readA((CURA), mi, 0); \
    _Pragma("unroll") for (int ni = 0; ni < 4; ++ni) bf0[ni] = readB((CURB), ni, 0); \
    /* stage t+1 (lands under this tile's MFMA shadow; covered by next tile) */ \
    if ((t_) + 1 < NT) {                                                        \
      const size_t ko_ = (size_t)((t_) + 1) * (BK * 2);                         \
      STAGE_A((NXTA), ko_, 0); STAGE_A((NXTA), ko_, 1);                         \
      STAGE_A((NXTA), ko_, 2); STAGE_A((NXTA), ko_, 3);                         \
      STAGE_B((NXTB), ko_, 0); STAGE_B((NXTB), ko_, 1);                         \
      STAGE_B((NXTB), ko_, 2); STAGE_B((NXTB), ko_, 3);                         \
      STAGE_B((NXTB), ko_, 4); STAGE_B((NXTB), ko_, 5);                         \
      STAGE_B((NXTB), ko_, 6); STAGE_B((NXTB), ko_, 7);                         \
    }                                                                           \
    _Pragma("unroll") for (int mi = 0; mi < 8; ++mi) af1[mi] = readA((CURA), mi, 1); \
    _Pragma("unroll") for (int ni = 0; ni < 4; ++ni) bf1[ni] = readB((CURB), ni, 1); \
    __builtin_amdgcn_s_setprio(1);                                              \
    _Pragma("unroll") for (int mi = 0; mi < 8; ++mi)                            \
      _Pragma("unroll") for (int ni = 0; ni < 4; ++ni)                          \
        acc[mi][ni] = __builtin_amdgcn_mfma_f32_16x16x32_bf16(                  \
            af0[mi], bf0[ni], acc[mi][ni], 0, 0, 0);                            \
    _Pragma("unroll") for (int mi = 0; mi < 8; ++mi)                            \
      _Pragma("unroll") for (int ni = 0; ni < 4; ++ni)                          \
        acc[mi][ni] = __builtin_amdgcn_mfma_f32_16x16x32_bf16(                  \
            af1[mi], bf1[ni], acc[mi][ni], 0, 0, 0);                            \
    __builtin_amdgcn_s_setprio(0);                                              \
    if ((t_) < NT - 1) {                                                        \
      __builtin_amdgcn_sched_barrier(0);                                        \
      asm volatile("s_waitcnt vmcnt(0)");  /* = t+1's 12 loads, issued ~1 tile ago */ \
    }                                                                           \
    __builtin_amdgcn_s_barrier();                                               \
  } while (0)

  {
    const short* A0 = As;         const short* B0 = Bs;
    const short* A1 = As + ASZ;   const short* B1 = Bs + BSZ;
    for (int t = 0; t < NT; t += 2) {
      TILE_BODY(t,     A0, B0, (char*)A1, (char*)B1);
      TILE_BODY(t + 1, A1, B1, (char*)A0, (char*)B0);
    }
  }

  // ---- epilogue: C/D map: col = lane&15, row = (lane>>4)*4 + reg
  const int cn = lane & 15;
  const int rb = (lane >> 4) * 4;
#pragma unroll
  for (int ai = 0; ai < 8; ++ai)
#pragma unroll
    for (int bj = 0; bj < 4; ++bj) {
      int m0 = bm + ai * 16 + rb;
      int n0 = bn + wc * 64 + bj * 16 + cn;
#pragma unroll
      for (int r = 0; r < 4; ++r)
        C[(size_t)(m0 + r) * N + n0] = acc[ai][bj][r];
    }
}

extern "C" void kernel_launch(void* const* d_in, const int* in_sizes, int n_in,
                              void* d_out, int out_size, void* d_ws, size_t ws_size,
                              hipStream_t stream) {
  const float* x   = (const float*)d_in[0];
  const float* wsc = (const float*)d_in[1];
  const int*   wq  = (const int*)d_in[2];
  float* out = (float*)d_out;

  const int K = 4096;                 // in_features
  const int N = in_sizes[2] / K;      // out_features = 4096
  const int M = in_sizes[0] / K;      // batch*seq = 2048

  // workspace layout: W bf16 [N*K] then X bf16 [M*K]
  short* Wb = (short*)d_ws;
  short* Xb = Wb + (size_t)N * K;

  int nblkW = (N * K) / 16;           // 1048576
  int n8    = (M * K) / 8;            // 1048576
  int gridP = (nblkW >> 8) + ((n8 + 255) >> 8);
  w4a16_prep<<<gridP, 256, 0, stream>>>(wq, wsc, Wb, nblkW, x, Xb, n8);

  dim3 grid(N / BN, M / BM);
  w4a16_gemm_w4<<<grid, 256, 0, stream>>>(Xb, Wb, out, M, N, K);
}

// Round 10
// 105.619 us; speedup vs baseline: 1.0437x; 1.0437x over previous
//
#include <hip/hip_runtime.h>

typedef __bf16  bf16x8 __attribute__((ext_vector_type(8)));
typedef float   f32x4  __attribute__((ext_vector_type(4)));
typedef short   short8 __attribute__((ext_vector_type(8)));

static __device__ __forceinline__ unsigned short f2bf(float f) {
  union { float f; unsigned int u; } v; v.f = f;
  unsigned int u = v.u;
  u += 0x7fffu + ((u >> 16) & 1u);   // round-to-nearest-even
  return (unsigned short)(u >> 16);
}

// e2m1 decode: code = sign<<3 | e<<1 | m ; values {0,.5,1,1.5,2,3,4,6} * sign
static __device__ __forceinline__ float fp4_decode(int qc) {
  int e = (qc >> 1) & 3;
  float m = (float)(qc & 1);
  float mag = (e == 0) ? (0.5f * m)
                       : ((2.0f + m) * 0.5f * (float)(1 << (e - 1)));
  return (qc & 8) ? -mag : mag;
}

// Fused prep: blocks [0, nblkW/256) dequant W (row-major, for LDS staging);
// rest convert x fp32 -> bf16 PACKED in MFMA A-fragment order:
//   chunk o: frag = o>>6, lane = o&63; mt = frag>>kshift, kt32 = frag&kmask;
//   fr = lane&15, kl = lane>>4;
//   Xp[o*8..+8] = bf16(x[mt*16+fr][kt32*32 + kl*8 .. +8])
// so a wave's A-frag load is frag_base + lane*16 (one coalesced 1KB line).
__global__ __launch_bounds__(256) void w4a16_prep(
    const int* __restrict__ wq, const float* __restrict__ wsc,
    short* __restrict__ wout, int nblkW,
    const float* __restrict__ x, short* __restrict__ xb, int n8,
    int K, int kshift) {
  const int nbW = nblkW >> 8;
  if ((int)blockIdx.x < nbW) {
    int idx = blockIdx.x * 256 + threadIdx.x;
    if (idx >= nblkW) return;
    float s = wsc[idx];
    const int4* qp = (const int4*)wq + (size_t)idx * 4;
    int4 q0 = qp[0], q1 = qp[1], q2 = qp[2], q3 = qp[3];
    short8 r0, r1;
    r0[0] = (short)f2bf(fp4_decode(q0.x) * s);
    r0[1] = (short)f2bf(fp4_decode(q0.y) * s);
    r0[2] = (short)f2bf(fp4_decode(q0.z) * s);
    r0[3] = (short)f2bf(fp4_decode(q0.w) * s);
    r0[4] = (short)f2bf(fp4_decode(q1.x) * s);
    r0[5] = (short)f2bf(fp4_decode(q1.y) * s);
    r0[6] = (short)f2bf(fp4_decode(q1.z) * s);
    r0[7] = (short)f2bf(fp4_decode(q1.w) * s);
    r1[0] = (short)f2bf(fp4_decode(q2.x) * s);
    r1[1] = (short)f2bf(fp4_decode(q2.y) * s);
    r1[2] = (short)f2bf(fp4_decode(q2.z) * s);
    r1[3] = (short)f2bf(fp4_decode(q2.w) * s);
    r1[4] = (short)f2bf(fp4_decode(q3.x) * s);
    r1[5] = (short)f2bf(fp4_decode(q3.y) * s);
    r1[6] = (short)f2bf(fp4_decode(q3.z) * s);
    r1[7] = (short)f2bf(fp4_decode(q3.w) * s);
    short8* op = (short8*)wout + (size_t)idx * 2;
    op[0] = r0;
    op[1] = r1;
  } else {
    int o = (blockIdx.x - nbW) * 256 + threadIdx.x;   // 16B chunk index
    if (o >= n8) return;
    int lane = o & 63, frag = o >> 6;
    int kt32 = frag & ((1 << kshift) - 1);
    int mt   = frag >> kshift;
    int fr = lane & 15, kl = lane >> 4;
    const float* xp = x + (size_t)(mt * 16 + fr) * K + kt32 * 32 + kl * 8;
    float4 a = ((const float4*)xp)[0], b = ((const float4*)xp)[1];
    short8 r;
    r[0] = (short)f2bf(a.x); r[1] = (short)f2bf(a.y);
    r[2] = (short)f2bf(a.z); r[3] = (short)f2bf(a.w);
    r[4] = (short)f2bf(b.x); r[5] = (short)f2bf(b.y);
    r[6] = (short)f2bf(b.z); r[7] = (short)f2bf(b.w);
    ((short8*)xb)[o] = r;
  }
}

// ---------------------------------------------------------------------------
// C[M,N] = A[M,K] * B[N,K]^T, bf16 in, fp32 out.
// R5's HW-PROVEN sync skeleton (passed, absmax 2.0) + packed-A dataflow:
// BM=128 x BN=256, BK=64, 8 waves (2x4), per-wave 64x64.
// A: PACKED fragment layout -> global_load_dwordx4 (frag_base + lane*16),
//    one coalesced line per load (fixes R5's 16-transaction gather),
//    double-buffered one tile ahead (static parity afA/afB).
// B: LDS double-buffer (64KB), global_load_lds w/ T2 source-swizzle, 1-ahead.
// One barrier per tile; boundary = sched_barrier + vmcnt(8) (drains B(t+1)x4,
// keeps A(t+1)x8 in flight; queue = [B(t+1):4][A(t+1):8]) + s_barrier.
// Prologue: B(0):4 + A(0):8 outstanding=12, vmcnt(8) retires exactly B(0).
// ---------------------------------------------------------------------------
#define BM 128
#define BN 256
#define BK 64
#define BSZ (BN * BK)          // shorts per B buffer (16384 = 32KB)

__global__ __launch_bounds__(512, 2) void w4a16_gemm_pk2(
    const short* __restrict__ Ap, const short* __restrict__ B,
    float* __restrict__ C, int M, int N, int K) {
  __shared__ __attribute__((aligned(16))) short Bs[2 * BSZ];  // 64KB

  const int tid  = threadIdx.x;
  const int lane = tid & 63;
  const int wid  = tid >> 6;      // 0..7
  const int wr   = wid >> 2;      // 0..1  (M)
  const int wc   = wid & 3;       // 0..3  (N)

  const int bm = blockIdx.y * BM;
  const int bn = blockIdx.x * BN;

  f32x4 acc[4][4] = {};           // [m-frag][n-frag]

  const int fr    = lane & 15;
  const int klane = lane >> 4;
  const int xv    = fr & 7;       // B read-side swizzle XOR

  const size_t rowbytes = (size_t)K * 2;
  const int    k32n     = K >> 5;           // k32 slices per row-tile (128)

  // ---- B staging addresses (loop-invariant; only kt varies)
  size_t boff[4];  int bldso[4];
#pragma unroll
  for (int r = 0; r < 4; ++r) {
    int u = r * 512 + tid;               // 0..2047
    int row = u >> 3, c = u & 7;
    int csrc = c ^ (row & 7);
    boff[r]  = (size_t)(bn + row) * rowbytes + (size_t)csrc * 16;
    bldso[r] = u * 16;
  }
  const char* Bg = (const char*)B;

#define STAGE_B(bufbase, koff2, r)                                              \
  __builtin_amdgcn_global_load_lds(                                             \
      (const __attribute__((address_space(1))) unsigned int*)(Bg + boff[r] + (koff2)), \
      (__attribute__((address_space(3))) unsigned int*)((char*)(bufbase) + bldso[r]),  \
      16, 0, 0)

  // ---- packed-A fragment loads (coalesced: frag_base + lane*16)
  const char* Apc = (const char*)Ap + (size_t)lane * 16;
  const int   amt = (bm >> 4) + wr * 4;      // wave's first 16-row tile
  auto loadA = [&](int mi, int k32) -> bf16x8 {
    size_t off = ((size_t)(amt + mi) * k32n + k32) << 10;   // *1024 bytes
    return *(const bf16x8*)(Apc + off);
  };

  // swizzled B fragment reads from LDS
  auto readB = [&](const short* Bb, int ni, int kk) -> bf16x8 {
    int row = wc * 64 + ni * 16 + fr;
    int c = kk * 4 + klane;
    return *(const bf16x8*)((const char*)Bb + (size_t)row * 128 + ((c ^ xv) << 4));
  };

  const int NT = K / BK;   // 64 (even)
  short* Bs0 = Bs;
  short* Bs1 = Bs + BSZ;

  bf16x8 bfr[4][2], afA[4][2], afB[4][2];

  // ---- prologue: stage B(0); load A(0) frags; drain B(0); publish.
  STAGE_B(Bs0, 0, 0); STAGE_B(Bs0, 0, 1); STAGE_B(Bs0, 0, 2); STAGE_B(Bs0, 0, 3);
  __builtin_amdgcn_sched_barrier(0);
#pragma unroll
  for (int mi = 0; mi < 4; ++mi)
#pragma unroll
    for (int kk = 0; kk < 2; ++kk)
      afA[mi][kk] = loadA(mi, kk);
  __builtin_amdgcn_sched_barrier(0);
  asm volatile("s_waitcnt vmcnt(8)");      // retire B(0); A(0) in flight
  __builtin_amdgcn_s_barrier();

#define TILE_BODY(t_, CURB, NXTB, AFU, AFL)                                     \
  do {                                                                          \
    _Pragma("unroll") for (int ni = 0; ni < 4; ++ni)                            \
      _Pragma("unroll") for (int kk = 0; kk < 2; ++kk)                          \
        bfr[ni][kk] = readB((CURB), ni, kk);                                    \
    const bool pf_ = (t_) + 1 < NT;                                             \
    if (pf_) {                                                                  \
      const size_t ko_ = (size_t)((t_) + 1) * (BK * 2);                         \
      STAGE_B((NXTB), ko_, 0); STAGE_B((NXTB), ko_, 1);                         \
      STAGE_B((NXTB), ko_, 2); STAGE_B((NXTB), ko_, 3);                         \
    }                                                                           \
    __builtin_amdgcn_sched_barrier(0);  /* pin: B-stage issued before A-loads */\
    if (pf_) {                                                                  \
      _Pragma("unroll") for (int mi = 0; mi < 4; ++mi)                          \
        _Pragma("unroll") for (int kk = 0; kk < 2; ++kk)                        \
          AFL[mi][kk] = loadA(mi, ((t_) + 1) * 2 + kk);                         \
    }                                                                           \
    __builtin_amdgcn_s_setprio(1);                                              \
    _Pragma("unroll") for (int mi = 0; mi < 4; ++mi)                            \
      _Pragma("unroll") for (int ni = 0; ni < 4; ++ni)                          \
        _Pragma("unroll") for (int kk = 0; kk < 2; ++kk)                        \
          acc[mi][ni] = __builtin_amdgcn_mfma_f32_16x16x32_bf16(                \
              AFU[mi][kk], bfr[ni][kk], acc[mi][ni], 0, 0, 0);                  \
    __builtin_amdgcn_s_setprio(0);                                              \
    if ((t_) < NT - 1) {                                                        \
      __builtin_amdgcn_sched_barrier(0);                                        \
      asm volatile("s_waitcnt vmcnt(8)");  /* drain B(t+1)x4; keep A(t+1)x8 */  \
      __builtin_amdgcn_s_barrier();                                             \
    }                                                                           \
  } while (0)

  for (int t = 0; t < NT; t += 2) {
    TILE_BODY(t,     Bs0, Bs1, afA, afB);
    TILE_BODY(t + 1, Bs1, Bs0, afB, afA);
  }

  // ---- epilogue: C/D map: col = lane&15, row = (lane>>4)*4 + reg
  const int cn = lane & 15;
  const int rb = (lane >> 4) * 4;
#pragma unroll
  for (int ai = 0; ai < 4; ++ai)
#pragma unroll
    for (int bj = 0; bj < 4; ++bj) {
      int m0 = bm + wr * 64 + ai * 16 + rb;
      int n0 = bn + wc * 64 + bj * 16 + cn;
#pragma unroll
      for (int r = 0; r < 4; ++r)
        C[(size_t)(m0 + r) * N + n0] = acc[ai][bj][r];
    }
}

extern "C" void kernel_launch(void* const* d_in, const int* in_sizes, int n_in,
                              void* d_out, int out_size, void* d_ws, size_t ws_size,
                              hipStream_t stream) {
  const float* x   = (const float*)d_in[0];
  const float* wsc = (const float*)d_in[1];
  const int*   wq  = (const int*)d_in[2];
  float* out = (float*)d_out;

  const int K = 4096;                 // in_features
  const int N = in_sizes[2] / K;      // out_features = 4096
  const int M = in_sizes[0] / K;      // batch*seq = 2048

  // workspace layout: W bf16 [N*K] then X bf16 packed [M*K]
  short* Wb = (short*)d_ws;
  short* Xb = Wb + (size_t)N * K;

  int nblkW = (N * K) / 16;           // 1048576
  int n8    = (M * K) / 8;            // 1048576
  int kshift = __builtin_ctz(K / 32); // 7
  int gridP = (nblkW >> 8) + ((n8 + 255) >> 8);
  w4a16_prep<<<gridP, 256, 0, stream>>>(wq, wsc, Wb, nblkW, x, Xb, n8, K, kshift);

  dim3 grid(N / BN, M / BM);
  w4a16_gemm_pk2<<<grid, 512, 0, stream>>>(Xb, Wb, out, M, N, K);
}

// Round 11
// 90.071 us; speedup vs baseline: 1.2238x; 1.1726x over previous
//
#include <hip/hip_runtime.h>

typedef __bf16  bf16x8 __attribute__((ext_vector_type(8)));
typedef float   f32x4  __attribute__((ext_vector_type(4)));
typedef short   short8 __attribute__((ext_vector_type(8)));

static __device__ __forceinline__ unsigned short f2bf(float f) {
  union { float f; unsigned int u; } v; v.f = f;
  unsigned int u = v.u;
  u += 0x7fffu + ((u >> 16) & 1u);   // round-to-nearest-even
  return (unsigned short)(u >> 16);
}

// e2m1 decode: code = sign<<3 | e<<1 | m ; values {0,.5,1,1.5,2,3,4,6} * sign
static __device__ __forceinline__ float fp4_decode(int qc) {
  int e = (qc >> 1) & 3;
  float m = (float)(qc & 1);
  float mag = (e == 0) ? (0.5f * m)
                       : ((2.0f + m) * 0.5f * (float)(1 << (e - 1)));
  return (qc & 8) ? -mag : mag;
}

// Fused prep (R4-proven): blocks [0, nblkW/256) dequant W; rest convert x
// (both row-major).
__global__ __launch_bounds__(256) void w4a16_prep(
    const int* __restrict__ wq, const float* __restrict__ wsc,
    short* __restrict__ wout, int nblkW,
    const float* __restrict__ x, short* __restrict__ xb, int n8) {
  const int nbW = nblkW >> 8;
  if ((int)blockIdx.x < nbW) {
    int idx = blockIdx.x * 256 + threadIdx.x;
    if (idx >= nblkW) return;
    float s = wsc[idx];
    const int4* qp = (const int4*)wq + (size_t)idx * 4;
    int4 q0 = qp[0], q1 = qp[1], q2 = qp[2], q3 = qp[3];
    short8 r0, r1;
    r0[0] = (short)f2bf(fp4_decode(q0.x) * s);
    r0[1] = (short)f2bf(fp4_decode(q0.y) * s);
    r0[2] = (short)f2bf(fp4_decode(q0.z) * s);
    r0[3] = (short)f2bf(fp4_decode(q0.w) * s);
    r0[4] = (short)f2bf(fp4_decode(q1.x) * s);
    r0[5] = (short)f2bf(fp4_decode(q1.y) * s);
    r0[6] = (short)f2bf(fp4_decode(q1.z) * s);
    r0[7] = (short)f2bf(fp4_decode(q1.w) * s);
    r1[0] = (short)f2bf(fp4_decode(q2.x) * s);
    r1[1] = (short)f2bf(fp4_decode(q2.y) * s);
    r1[2] = (short)f2bf(fp4_decode(q2.z) * s);
    r1[3] = (short)f2bf(fp4_decode(q2.w) * s);
    r1[4] = (short)f2bf(fp4_decode(q3.x) * s);
    r1[5] = (short)f2bf(fp4_decode(q3.y) * s);
    r1[6] = (short)f2bf(fp4_decode(q3.z) * s);
    r1[7] = (short)f2bf(fp4_decode(q3.w) * s);
    short8* op = (short8*)wout + (size_t)idx * 2;
    op[0] = r0;
    op[1] = r1;
  } else {
    int idx = (blockIdx.x - nbW) * 256 + threadIdx.x;
    if (idx >= n8) return;
    const float4* xp = (const float4*)x + (size_t)idx * 2;
    float4 a = xp[0], b = xp[1];
    short8 r;
    r[0] = (short)f2bf(a.x); r[1] = (short)f2bf(a.y);
    r[2] = (short)f2bf(a.z); r[3] = (short)f2bf(a.w);
    r[4] = (short)f2bf(b.x); r[5] = (short)f2bf(b.y);
    r[6] = (short)f2bf(b.z); r[7] = (short)f2bf(b.w);
    ((short8*)xb)[idx] = r;
  }
}

// ---------------------------------------------------------------------------
// C[M,N] = A[M,K] * B[N,K]^T, bf16 in, fp32 out.
// R4's proven skeleton (BM=128 x BN=256, BK=64, 8 waves 2x4, NBUF=3,
// stage-2-ahead, one vmcnt(6)+barrier per tile) + READ-AHEAD pipelining:
// frags(t+1) are ds_read into a second register set AFTER the mid-tile
// publish (vmcnt(6)+barrier) and OVERLAP the second half of tile t's MFMA.
// Body(t): stage(t+2) -> 16 MFMA chunkA on rf(t) -> SB -> vmcnt(6) ->
//   s_barrier -> 16 ds_read frags(t+1)->rf_other -> 16 MFMA chunkB on rf(t).
// Safety audit (all R4-inherited):
//  - vmcnt(6) at mid(t): queue = [stage(t+2):6][stage(t+1):6] -> retires
//    t+1 (own writes); barrier joins all waves => t+1 published for reads.
//  - stage(t+2) writes buf (t-1)%3: its reads (body(t-2)) are lgkm-drained
//    before chunkA(t-1), which precedes mid-barrier(t-1) < stage(t+2). OK.
//  - prologue: stage(0),(1) = 12 outstanding; vmcnt(6) retires tile 0.
// Swizzle (T2, R2-verified): 16B-chunk c XOR (row&7) on SOURCE and READ.
// ---------------------------------------------------------------------------
#define BM 128
#define BN 256
#define BK 64
#define NBUF 3
#define ASZ (BM * BK)          // 8192 shorts = 16KB
#define BSZ (BN * BK)          // 16384 shorts = 32KB

__global__ __launch_bounds__(512, 1) void w4a16_gemm_ra(
    const short* __restrict__ A, const short* __restrict__ B,
    float* __restrict__ C, int M, int N, int K) {
  __shared__ __attribute__((aligned(16))) short As[NBUF * ASZ];  // 48KB
  __shared__ __attribute__((aligned(16))) short Bs[NBUF * BSZ];  // 96KB

  const int tid  = threadIdx.x;
  const int lane = tid & 63;
  const int wid  = tid >> 6;      // 0..7
  const int wr   = wid >> 2;      // 0..1  (M)
  const int wc   = wid & 3;       // 0..3  (N)

  const int bm = blockIdx.y * BM;
  const int bn = blockIdx.x * BN;

  f32x4 acc[4][4] = {};           // [m-frag][n-frag]

  const int fr    = lane & 15;
  const int klane = lane >> 4;
  const int xv    = fr & 7;       // read-side swizzle XOR

  const size_t rowbytes = (size_t)K * 2;

  // ---- loop-invariant staging addresses (per-thread): only kt varies.
  size_t aoff[2];  int aldso[2];
#pragma unroll
  for (int r = 0; r < 2; ++r) {
    int u = r * 512 + tid;               // 0..1023
    int row = u >> 3, c = u & 7;
    int csrc = c ^ (row & 7);
    aoff[r]  = (size_t)(bm + row) * rowbytes + (size_t)csrc * 16;
    aldso[r] = u * 16;
  }
  size_t boff[4];  int bldso[4];
#pragma unroll
  for (int r = 0; r < 4; ++r) {
    int u = r * 512 + tid;               // 0..2047
    int row = u >> 3, c = u & 7;
    int csrc = c ^ (row & 7);
    boff[r]  = (size_t)(bn + row) * rowbytes + (size_t)csrc * 16;
    bldso[r] = u * 16;
  }

  const char* Ag = (const char*)A;
  const char* Bg = (const char*)B;

#define STAGE_A(bufbase, koff2, r)                                              \
  __builtin_amdgcn_global_load_lds(                                             \
      (const __attribute__((address_space(1))) unsigned int*)(Ag + aoff[r] + (koff2)), \
      (__attribute__((address_space(3))) unsigned int*)((char*)(bufbase) + aldso[r]),  \
      16, 0, 0)
#define STAGE_B(bufbase, koff2, r)                                              \
  __builtin_amdgcn_global_load_lds(                                             \
      (const __attribute__((address_space(1))) unsigned int*)(Bg + boff[r] + (koff2)), \
      (__attribute__((address_space(3))) unsigned int*)((char*)(bufbase) + bldso[r]),  \
      16, 0, 0)

  // swizzled fragment reads
  auto readA = [&](const short* Ab, int mi, int kk) -> bf16x8 {
    int row = wr * 64 + mi * 16 + fr;
    int c = kk * 4 + klane;
    return *(const bf16x8*)((const char*)Ab + (size_t)row * 128 + ((c ^ xv) << 4));
  };
  auto readB = [&](const short* Bb, int ni, int kk) -> bf16x8 {
    int row = wc * 64 + ni * 16 + fr;
    int c = kk * 4 + klane;
    return *(const bf16x8*)((const char*)Bb + (size_t)row * 128 + ((c ^ xv) << 4));
  };

  const int NT = K / BK;   // 64 (even)

  bf16x8 afA[4][2], bfA[4][2], afB[4][2], bfB[4][2];

  // ---- prologue: stage tiles 0,1; retire tile 0; publish; read frags(0).
  {
    char* A0 = (char*)As; char* B0 = (char*)Bs;
    char* A1 = (char*)(As + ASZ); char* B1 = (char*)(Bs + BSZ);
    STAGE_A(A0, 0, 0); STAGE_A(A0, 0, 1);
    STAGE_B(B0, 0, 0); STAGE_B(B0, 0, 1); STAGE_B(B0, 0, 2); STAGE_B(B0, 0, 3);
    size_t k2 = (size_t)BK * 2;
    STAGE_A(A1, k2, 0); STAGE_A(A1, k2, 1);
    STAGE_B(B1, k2, 0); STAGE_B(B1, k2, 1); STAGE_B(B1, k2, 2); STAGE_B(B1, k2, 3);
  }
  __builtin_amdgcn_sched_barrier(0);
  asm volatile("s_waitcnt vmcnt(6)");      // tile 0 resident; tile 1 in flight
  __builtin_amdgcn_s_barrier();
  __builtin_amdgcn_sched_barrier(0);
#pragma unroll
  for (int mi = 0; mi < 4; ++mi)
#pragma unroll
    for (int kk = 0; kk < 2; ++kk)
      afA[mi][kk] = readA(As, mi, kk);
#pragma unroll
  for (int ni = 0; ni < 4; ++ni)
#pragma unroll
    for (int kk = 0; kk < 2; ++kk)
      bfA[ni][kk] = readB(Bs, ni, kk);

  int nr = 1, ns = 2;   // nr = buf holding tile t+1; ns = stage dest (t+2)

#define TILE_BODY(t_, AFU, BFU, AFL, BFL)                                       \
  do {                                                                          \
    if ((t_) + 2 < NT) {                                                        \
      char* An = (char*)(As + ns * ASZ);                                        \
      char* Bn = (char*)(Bs + ns * BSZ);                                        \
      const size_t ko_ = (size_t)((t_) + 2) * (BK * 2);                         \
      STAGE_A(An, ko_, 0); STAGE_A(An, ko_, 1);                                 \
      STAGE_B(Bn, ko_, 0); STAGE_B(Bn, ko_, 1);                                 \
      STAGE_B(Bn, ko_, 2); STAGE_B(Bn, ko_, 3);                                 \
    }                                                                           \
    __builtin_amdgcn_s_setprio(1);                                              \
    _Pragma("unroll") for (int mi = 0; mi < 2; ++mi)                            \
      _Pragma("unroll") for (int ni = 0; ni < 4; ++ni)                          \
        _Pragma("unroll") for (int kk = 0; kk < 2; ++kk)                        \
          acc[mi][ni] = __builtin_amdgcn_mfma_f32_16x16x32_bf16(                \
              AFU[mi][kk], BFU[ni][kk], acc[mi][ni], 0, 0, 0);                  \
    __builtin_amdgcn_s_setprio(0);                                              \
    __builtin_amdgcn_sched_barrier(0);                                          \
    if ((t_) + 1 < NT) {                                                        \
      if ((t_) + 2 < NT) asm volatile("s_waitcnt vmcnt(6)");                    \
      else               asm volatile("s_waitcnt vmcnt(0)");                    \
      __builtin_amdgcn_s_barrier();     /* publish tile t+1 */                  \
      __builtin_amdgcn_sched_barrier(0);                                        \
      const short* Ar = As + nr * ASZ;                                          \
      const short* Br = Bs + nr * BSZ;                                          \
      _Pragma("unroll") for (int mi = 0; mi < 4; ++mi)                          \
        _Pragma("unroll") for (int kk = 0; kk < 2; ++kk)                        \
          AFL[mi][kk] = readA(Ar, mi, kk);                                      \
      _Pragma("unroll") for (int ni = 0; ni < 4; ++ni)                          \
        _Pragma("unroll") for (int kk = 0; kk < 2; ++kk)                        \
          BFL[ni][kk] = readB(Br, ni, kk);                                      \
      __builtin_amdgcn_sched_barrier(0);                                        \
    }                                                                           \
    __builtin_amdgcn_s_setprio(1);                                              \
    _Pragma("unroll") for (int mi = 2; mi < 4; ++mi)                            \
      _Pragma("unroll") for (int ni = 0; ni < 4; ++ni)                          \
        _Pragma("unroll") for (int kk = 0; kk < 2; ++kk)                        \
          acc[mi][ni] = __builtin_amdgcn_mfma_f32_16x16x32_bf16(                \
              AFU[mi][kk], BFU[ni][kk], acc[mi][ni], 0, 0, 0);                  \
    __builtin_amdgcn_s_setprio(0);                                              \
    nr = ns; ns = (ns == NBUF - 1) ? 0 : ns + 1;                                \
  } while (0)

  for (int t = 0; t < NT; t += 2) {
    TILE_BODY(t,     afA, bfA, afB, bfB);
    TILE_BODY(t + 1, afB, bfB, afA, bfA);
  }

  // ---- epilogue: C/D map: col = lane&15, row = (lane>>4)*4 + reg
  const int cn = lane & 15;
  const int rb = (lane >> 4) * 4;
#pragma unroll
  for (int ai = 0; ai < 4; ++ai)
#pragma unroll
    for (int bj = 0; bj < 4; ++bj) {
      int m0 = bm + wr * 64 + ai * 16 + rb;
      int n0 = bn + wc * 64 + bj * 16 + cn;
#pragma unroll
      for (int r = 0; r < 4; ++r)
        C[(size_t)(m0 + r) * N + n0] = acc[ai][bj][r];
    }
}

extern "C" void kernel_launch(void* const* d_in, const int* in_sizes, int n_in,
                              void* d_out, int out_size, void* d_ws, size_t ws_size,
                              hipStream_t stream) {
  const float* x   = (const float*)d_in[0];
  const float* wsc = (const float*)d_in[1];
  const int*   wq  = (const int*)d_in[2];
  float* out = (float*)d_out;

  const int K = 4096;                 // in_features
  const int N = in_sizes[2] / K;      // out_features = 4096
  const int M = in_sizes[0] / K;      // batch*seq = 2048

  // workspace layout: W bf16 [N*K] then X bf16 [M*K]
  short* Wb = (short*)d_ws;
  short* Xb = Wb + (size_t)N * K;

  int nblkW = (N * K) / 16;           // 1048576
  int n8    = (M * K) / 8;            // 1048576
  int gridP = (nblkW >> 8) + ((n8 + 255) >> 8);
  w4a16_prep<<<gridP, 256, 0, stream>>>(wq, wsc, Wb, nblkW, x, Xb, n8);

  dim3 grid(N / BN, M / BM);
  w4a16_gemm_ra<<<grid, 512, 0, stream>>>(Xb, Wb, out, M, N, K);
}